// Round 1
// baseline (567.563 us; speedup 1.0000x reference)
//
#include <hip/hip_runtime.h>
#include <hip/hip_bf16.h>
#include <math.h>

#define Bn 8
#define Nn 8192
#define KIN 1024
#define DOUT 512
#define NC 64
#define LN_EPS 1e-5f

typedef short bf16x8 __attribute__((ext_vector_type(8)));
typedef short s8v __attribute__((ext_vector_type(8)));
typedef short s4v __attribute__((ext_vector_type(4)));
typedef float f32x4 __attribute__((ext_vector_type(4)));

__device__ __forceinline__ short f2bf(float f) {
    __hip_bfloat16 h = __float2bfloat16(f);
    return __builtin_bit_cast(short, h);
}

__device__ __forceinline__ void load_lds16(const void* g, void* l) {
    __builtin_amdgcn_global_load_lds(
        (const __attribute__((address_space(1))) unsigned int*)g,
        (__attribute__((address_space(3))) unsigned int*)l, 16, 0, 0);
}

// ---------------- prep: W_node^T -> bf16 [512][1024], LDS transpose ----------------
__global__ __launch_bounds__(256) void k_prep_w(const float* __restrict__ W,
                                                short* __restrict__ Wt) {
    __shared__ short L[64 * 72];
    const int tid = threadIdx.x;
    const int kt = blockIdx.x >> 3, nt = blockIdx.x & 7;   // 16 x 8 tiles of 64x64
    const int k0 = kt * 64, n0 = nt * 64;
    {
        int r = tid >> 2, c0 = (tid & 3) * 16;   // k-row r, 16 n per thread
        const float* g = W + (size_t)(k0 + r) * DOUT + n0 + c0;
        float4 a0 = *reinterpret_cast<const float4*>(g);
        float4 a1 = *reinterpret_cast<const float4*>(g + 4);
        float4 a2 = *reinterpret_cast<const float4*>(g + 8);
        float4 a3 = *reinterpret_cast<const float4*>(g + 12);
        s8v p0, p1;
        p0[0]=f2bf(a0.x); p0[1]=f2bf(a0.y); p0[2]=f2bf(a0.z); p0[3]=f2bf(a0.w);
        p0[4]=f2bf(a1.x); p0[5]=f2bf(a1.y); p0[6]=f2bf(a1.z); p0[7]=f2bf(a1.w);
        p1[0]=f2bf(a2.x); p1[1]=f2bf(a2.y); p1[2]=f2bf(a2.z); p1[3]=f2bf(a2.w);
        p1[4]=f2bf(a3.x); p1[5]=f2bf(a3.y); p1[6]=f2bf(a3.z); p1[7]=f2bf(a3.w);
        *reinterpret_cast<s8v*>(&L[r * 72 + c0]) = p0;
        *reinterpret_cast<s8v*>(&L[r * 72 + c0 + 8]) = p1;
    }
    __syncthreads();
    {
        int n = tid >> 2, kc = (tid & 3) * 16;   // n-row, 16 k per thread
        s8v y0, y1;
#pragma unroll
        for (int j = 0; j < 8; ++j) y0[j] = L[(kc + j) * 72 + n];
#pragma unroll
        for (int j = 0; j < 8; ++j) y1[j] = L[(kc + 8 + j) * 72 + n];
        short* o = Wt + (size_t)(n0 + n) * KIN + k0 + kc;
        *reinterpret_cast<s8v*>(o) = y0;
        *reinterpret_cast<s8v*>(o + 8) = y1;
    }
}

// ---------------- prep: ccp = cc @ Wc + bc (fp32 + bf16), coalesced ----------------
__global__ __launch_bounds__(256) void k_prep_c(
    const float* __restrict__ cc, const float* __restrict__ Wc,
    const float* __restrict__ bc, float* __restrict__ ccp_f,
    short* __restrict__ ccp_bf) {
    __shared__ float ccs[512];
    const int tid = threadIdx.x, c = blockIdx.x;
    ccs[tid] = cc[c * DOUT + tid];
    ccs[tid + 256] = cc[c * DOUT + tid + 256];
    __syncthreads();
    float a0 = bc[tid], a1 = bc[tid + 256];
    for (int k = 0; k < DOUT; ++k) {
        float s = ccs[k];
        a0 += s * Wc[(size_t)k * DOUT + tid];
        a1 += s * Wc[(size_t)k * DOUT + tid + 256];
    }
    ccp_f[c * DOUT + tid] = a0;
    ccp_f[c * DOUT + tid + 256] = a1;
    ccp_bf[c * DOUT + tid] = f2bf(a0);
    ccp_bf[c * DOUT + tid + 256] = f2bf(a1);
}

// ---------------- GEMM1: proj & projT = A(fp32) @ W + b ----------------
// BM=64 x BN=512(full) x BK=32: A read from HBM exactly once. 256 thr / 4 waves,
// wave tile 64x128 (32 MFMA : 12 ds_read_b128 per iter). Wt (1 MB) L2-resident.
// Epilogue writes proj [n-major] AND projT [m-major] (replaces transpose kernel).
__global__ __launch_bounds__(256, 2) void k_gemm1(
    const float* __restrict__ A, const short* __restrict__ Wt,
    const float* __restrict__ bias, short* __restrict__ proj,
    short* __restrict__ projT) {
    __shared__ short As[64 * 40];     // padded stride 40
    __shared__ short Bs[512 * 32];
    const int tid = threadIdx.x, lane = tid & 63, wv = tid >> 6;
    const int quad = lane >> 4, l15 = lane & 15;
    const int m0 = blockIdx.x * 64;

    f32x4 acc[4][8];
#pragma unroll
    for (int i = 0; i < 4; ++i)
#pragma unroll
        for (int j = 0; j < 8; ++j) acc[i][j] = (f32x4){0.f, 0.f, 0.f, 0.f};

    const int ar = tid >> 2;            // 0..63 A row
    const int ac = (tid & 2) * 8;       // 0 / 16  (two float4 pairs below)
    const int ac2 = (tid & 3) * 8;      // 8-float group
    const float* Ag = A + (size_t)(m0 + ar) * KIN + ac2;

    for (int it = 0; it < KIN / 32; ++it) {
        const int k0 = it * 32;
        __syncthreads();
        {   // A: 64x32 fp32 -> bf16; 8 floats/thread -> one ds_write_b128
            float4 a0 = *reinterpret_cast<const float4*>(Ag + k0);
            float4 a1 = *reinterpret_cast<const float4*>(Ag + k0 + 4);
            s8v p;
            p[0]=f2bf(a0.x); p[1]=f2bf(a0.y); p[2]=f2bf(a0.z); p[3]=f2bf(a0.w);
            p[4]=f2bf(a1.x); p[5]=f2bf(a1.y); p[6]=f2bf(a1.z); p[7]=f2bf(a1.w);
            *reinterpret_cast<s8v*>(&As[ar * 40 + ac2]) = p;
        }
#pragma unroll
        for (int i = 0; i < 8; ++i) {   // B: 512x32 bf16 = 2048 chunks of 16B
            int c = i * 256 + tid;
            int n = c >> 2, kc = c & 3;
            load_lds16(Wt + (size_t)n * KIN + k0 + kc * 8,
                       Bs + (i * 256 + wv * 64) * 8);
        }
        __syncthreads();
        bf16x8 af[4], bfr[8];
#pragma unroll
        for (int mi = 0; mi < 4; ++mi)
            af[mi] = *reinterpret_cast<const bf16x8*>(&As[(mi * 16 + l15) * 40 + quad * 8]);
#pragma unroll
        for (int ni = 0; ni < 8; ++ni)
            bfr[ni] = *reinterpret_cast<const bf16x8*>(&Bs[(wv * 128 + ni * 16 + l15) * 32 + quad * 8]);
#pragma unroll
        for (int mi = 0; mi < 4; ++mi)
#pragma unroll
            for (int ni = 0; ni < 8; ++ni)
                acc[mi][ni] = __builtin_amdgcn_mfma_f32_16x16x32_bf16(af[mi], bfr[ni], acc[mi][ni], 0, 0, 0);
    }
    // epilogue: +bias; write proj[row][col] (2B) and projT[col][row] (8B packed)
#pragma unroll
    for (int ni = 0; ni < 8; ++ni) {
        int col = wv * 128 + ni * 16 + l15;
        float bv = bias[col];
#pragma unroll
        for (int mi = 0; mi < 4; ++mi) {
            int row0 = m0 + mi * 16 + quad * 4;
            s4v t;
#pragma unroll
            for (int r = 0; r < 4; ++r) {
                short v = f2bf(acc[mi][ni][r] + bv);
                t[r] = v;
                proj[(size_t)(row0 + r) * DOUT + col] = v;
            }
            *reinterpret_cast<s4v*>(projT + (size_t)col * (Bn * Nn) + row0) = t;
        }
    }
}

// ---------------- sims[b][c][n] = ccp . proj  (K=512) ----------------
// block 64c x 128n, 256 thr / 4 waves, wave 32x64, BK=32, 16 iters.
__global__ __launch_bounds__(256) void k_sims(
    const short* __restrict__ ccp_bf, const short* __restrict__ proj,
    float* __restrict__ sims) {
    __shared__ short As[64 * 32];
    __shared__ short Bs[128 * 32];
    const int tid = threadIdx.x, lane = tid & 63, wv = tid >> 6;
    const int quad = lane >> 4, l15 = lane & 15;
    const int b = blockIdx.x >> 6, nt = blockIdx.x & 63;
    const int n0 = nt * 128;
    const int wm = wv & 1, wn = wv >> 1;

    f32x4 acc[2][4];
#pragma unroll
    for (int i = 0; i < 2; ++i)
#pragma unroll
        for (int j = 0; j < 4; ++j) acc[i][j] = (f32x4){0.f, 0.f, 0.f, 0.f};

    for (int it = 0; it < DOUT / 32; ++it) {
        const int k0 = it * 32;
        __syncthreads();
        {   // A: 64x32 = 512 chunks, 2/thread
#pragma unroll
            for (int i = 0; i < 2; ++i) {
                int c = i * 256 + tid;
                int r = c >> 2, kc = c & 3;
                load_lds16(ccp_bf + (size_t)r * DOUT + k0 + kc * 8,
                           As + (i * 256 + wv * 64) * 8);
            }
        }
#pragma unroll
        for (int i = 0; i < 2; ++i) {   // B: 128x32 = 512 chunks
            int c = i * 256 + tid;
            int r = c >> 2, kc = c & 3;
            load_lds16(proj + (size_t)(b * Nn + n0 + r) * DOUT + k0 + kc * 8,
                       Bs + (i * 256 + wv * 64) * 8);
        }
        __syncthreads();
        bf16x8 af[2], bfr[4];
#pragma unroll
        for (int mi = 0; mi < 2; ++mi)
            af[mi] = *reinterpret_cast<const bf16x8*>(&As[(wm * 32 + mi * 16 + l15) * 32 + quad * 8]);
#pragma unroll
        for (int ni = 0; ni < 4; ++ni)
            bfr[ni] = *reinterpret_cast<const bf16x8*>(&Bs[(wn * 64 + ni * 16 + l15) * 32 + quad * 8]);
#pragma unroll
        for (int mi = 0; mi < 2; ++mi)
#pragma unroll
            for (int ni = 0; ni < 4; ++ni)
                acc[mi][ni] = __builtin_amdgcn_mfma_f32_16x16x32_bf16(af[mi], bfr[ni], acc[mi][ni], 0, 0, 0);
    }
#pragma unroll
    for (int mi = 0; mi < 2; ++mi)
#pragma unroll
        for (int ni = 0; ni < 4; ++ni)
#pragma unroll
            for (int r = 0; r < 4; ++r) {
                int c = wm * 32 + mi * 16 + quad * 4 + r;
                int n = n0 + wn * 64 + ni * 16 + l15;
                sims[((size_t)b * NC + c) * Nn + n] = acc[mi][ni][r];
            }
}

// ---------------- softmax over n (in-place on d_out) + bf16 copy ----------------
__global__ __launch_bounds__(256) void k_softmax(
    float* __restrict__ aw, const unsigned char* __restrict__ mask,
    short* __restrict__ aw_bf) {
    __shared__ float red[8];
    const int tid = threadIdx.x, lane = tid & 63, wv = tid >> 6;
    const int b = blockIdx.x >> 6, c = blockIdx.x & 63;
    float* p = aw + ((size_t)b * NC + c) * Nn;
    short* q = aw_bf + ((size_t)b * NC + c) * Nn;
    const unsigned char* mp = mask + b * Nn;

    float v[32];
    float mx = -INFINITY;
#pragma unroll
    for (int i = 0; i < 32; ++i) {
        int idx = tid + i * 256;
        float x = p[idx];
        if (mp[idx]) x = -INFINITY;
        v[i] = x;
        mx = fmaxf(mx, x);
    }
    for (int off = 32; off; off >>= 1) mx = fmaxf(mx, __shfl_xor(mx, off));
    if (lane == 0) red[wv] = mx;
    __syncthreads();
    mx = fmaxf(fmaxf(red[0], red[1]), fmaxf(red[2], red[3]));
    __syncthreads();

    float s = 0.f;
#pragma unroll
    for (int i = 0; i < 32; ++i) {
        v[i] = expf(v[i] - mx);
        s += v[i];
    }
    for (int off = 32; off; off >>= 1) s += __shfl_xor(s, off);
    if (lane == 0) red[wv] = s;
    __syncthreads();
    s = red[0] + red[1] + red[2] + red[3];
    float inv = 1.f / s;
#pragma unroll
    for (int i = 0; i < 32; ++i) {
        int idx = tid + i * 256;
        float w = v[i] * inv;
        p[idx] = w;
        q[idx] = f2bf(w);
    }
}

// ---------------- aggregation: partial[b][ks][c][d], split-K=8 ----------------
// A = aw_bf [c][n] k-major, B = projT [d][n] k-major. block 64c x 128d,
// BK=32, 32 iters over ks-chunk of 1024. 256 thr / 4 waves, wave 32x64.
__global__ __launch_bounds__(256) void k_agg(
    const short* __restrict__ aw_bf, const short* __restrict__ projT,
    float* __restrict__ partial) {
    __shared__ short As[64 * 32];
    __shared__ short Bs[128 * 32];
    const int tid = threadIdx.x, lane = tid & 63, wv = tid >> 6;
    const int quad = lane >> 4, l15 = lane & 15;
    const int b = blockIdx.x >> 5, dt = (blockIdx.x >> 3) & 3, ks = blockIdx.x & 7;
    const int d0 = dt * 128;
    const int wm = wv & 1, wn = wv >> 1;

    f32x4 acc[2][4];
#pragma unroll
    for (int i = 0; i < 2; ++i)
#pragma unroll
        for (int j = 0; j < 4; ++j) acc[i][j] = (f32x4){0.f, 0.f, 0.f, 0.f};

    for (int it = 0; it < 32; ++it) {
        const int nb = ks * 1024 + it * 32;
        __syncthreads();
#pragma unroll
        for (int i = 0; i < 2; ++i) {   // A: 64c x 32n
            int c = i * 256 + tid;
            int r = c >> 2, kc = c & 3;
            load_lds16(aw_bf + ((size_t)b * NC + r) * Nn + nb + kc * 8,
                       As + (i * 256 + wv * 64) * 8);
        }
#pragma unroll
        for (int i = 0; i < 2; ++i) {   // B: 128d x 32n
            int c = i * 256 + tid;
            int r = c >> 2, kc = c & 3;
            load_lds16(projT + (size_t)(d0 + r) * (Bn * Nn) + b * Nn + nb + kc * 8,
                       Bs + (i * 256 + wv * 64) * 8);
        }
        __syncthreads();
        bf16x8 af[2], bfr[4];
#pragma unroll
        for (int mi = 0; mi < 2; ++mi)
            af[mi] = *reinterpret_cast<const bf16x8*>(&As[(wm * 32 + mi * 16 + l15) * 32 + quad * 8]);
#pragma unroll
        for (int ni = 0; ni < 4; ++ni)
            bfr[ni] = *reinterpret_cast<const bf16x8*>(&Bs[(wn * 64 + ni * 16 + l15) * 32 + quad * 8]);
#pragma unroll
        for (int mi = 0; mi < 2; ++mi)
#pragma unroll
            for (int ni = 0; ni < 4; ++ni)
                acc[mi][ni] = __builtin_amdgcn_mfma_f32_16x16x32_bf16(af[mi], bfr[ni], acc[mi][ni], 0, 0, 0);
    }
#pragma unroll
    for (int mi = 0; mi < 2; ++mi)
#pragma unroll
        for (int ni = 0; ni < 4; ++ni)
#pragma unroll
            for (int r = 0; r < 4; ++r) {
                int c = wm * 32 + mi * 16 + quad * 4 + r;
                int d = d0 + wn * 64 + ni * 16 + l15;
                partial[(((size_t)b * 8 + ks) * NC + c) * DOUT + d] = acc[mi][ni][r];
            }
}

// ---------------- LN: sum partials + ccp residual, normalize, store ----------------
__global__ __launch_bounds__(256) void k_ln(
    const float* __restrict__ partial, const float* __restrict__ ccp,
    const float* __restrict__ gamma, const float* __restrict__ beta,
    float* __restrict__ out) {
    __shared__ float red[16];
    const int tid = threadIdx.x, lane = tid & 63, wv = tid >> 6;
    const int b = blockIdx.x >> 6, c = blockIdx.x & 63;
    float v0 = ccp[c * DOUT + tid], v1 = ccp[c * DOUT + tid + 256];
#pragma unroll
    for (int ks = 0; ks < 8; ++ks) {
        const float* pp = partial + (((size_t)b * 8 + ks) * NC + c) * DOUT;
        v0 += pp[tid];
        v1 += pp[tid + 256];
    }
    float s = v0 + v1, sq = v0 * v0 + v1 * v1;
    for (int off = 32; off; off >>= 1) {
        s += __shfl_xor(s, off);
        sq += __shfl_xor(sq, off);
    }
    if (lane == 0) { red[wv] = s; red[8 + wv] = sq; }
    __syncthreads();
    s = red[0] + red[1] + red[2] + red[3];
    sq = red[8] + red[9] + red[10] + red[11];
    float mu = s * (1.f / 512.f);
    float var = sq * (1.f / 512.f) - mu * mu;
    float rs = rsqrtf(var + LN_EPS);
    size_t base = ((size_t)b * NC + c) * DOUT;
    out[base + tid] = (v0 - mu) * rs * gamma[tid] + beta[tid];
    out[base + tid + 256] = (v1 - mu) * rs * gamma[tid + 256] + beta[tid + 256];
}

extern "C" void kernel_launch(void* const* d_in, const int* in_sizes, int n_in,
                              void* d_out, int out_size, void* d_ws, size_t ws_size,
                              hipStream_t stream) {
    const float* node_emb = (const float*)d_in[0];
    const unsigned char* mask = (const unsigned char*)d_in[1];
    const float* cc = (const float*)d_in[2];
    const float* Wn = (const float*)d_in[3];
    const float* bn = (const float*)d_in[4];
    const float* Wc = (const float*)d_in[5];
    const float* bc = (const float*)d_in[6];
    const float* gamma = (const float*)d_in[7];
    const float* beta = (const float*)d_in[8];
    float* out = (float*)d_out;

    char* ws = (char*)d_ws;
    short* proj   = (short*)(ws);                   //  67,108,864 B  [65536][512] bf16
    short* projT  = (short*)(ws + 67108864);        //  67,108,864 B  [512][65536] bf16
    short* aw_bf  = (short*)(ws + 134217728);       //   8,388,608 B  [8][64][8192] bf16
    float* ccp_f  = (float*)(ws + 142606336);       //     131,072 B
    short* ccp_bf = (short*)(ws + 142737408);       //      65,536 B
    short* Wt     = (short*)(ws + 142802944);       //   1,048,576 B  [512][1024] bf16
    float* partial= (float*)(ws + 143851520);       //   8,388,608 B  [8][8][64][512] f32

    float* sims = out + (size_t)Bn * NC * DOUT;     // aw region of d_out, scratch

    k_prep_w<<<128, 256, 0, stream>>>(Wn, Wt);
    k_prep_c<<<64, 256, 0, stream>>>(cc, Wc, bc, ccp_f, ccp_bf);
    k_gemm1<<<1024, 256, 0, stream>>>(node_emb, Wt, bn, proj, projT);
    k_sims<<<512, 256, 0, stream>>>(ccp_bf, proj, sims);
    k_softmax<<<512, 256, 0, stream>>>(sims, mask, aw_bf);
    k_agg<<<256, 256, 0, stream>>>(aw_bf, projT, partial);
    k_ln<<<512, 256, 0, stream>>>(partial, ccp_f, gamma, beta, out);
}

// Round 3
// 551.816 us; speedup vs baseline: 1.0285x; 1.0285x over previous
//
#include <hip/hip_runtime.h>
#include <hip/hip_bf16.h>
#include <math.h>

#define Bn 8
#define Nn 8192
#define KIN 1024
#define DOUT 512
#define NC 64
#define LN_EPS 1e-5f

typedef short bf16x8 __attribute__((ext_vector_type(8)));
typedef short s8v __attribute__((ext_vector_type(8)));
typedef short s4v __attribute__((ext_vector_type(4)));
typedef float f32x4 __attribute__((ext_vector_type(4)));

__device__ __forceinline__ short f2bf(float f) {
    __hip_bfloat16 h = __float2bfloat16(f);
    return __builtin_bit_cast(short, h);
}

__device__ __forceinline__ void load_lds16(const void* g, void* l) {
    __builtin_amdgcn_global_load_lds(
        (const __attribute__((address_space(1))) unsigned int*)g,
        (__attribute__((address_space(3))) unsigned int*)l, 16, 0, 0);
}

// ---------------- prep: W_node^T -> bf16 [512][1024], LDS transpose ----------------
__global__ __launch_bounds__(256) void k_prep_w(const float* __restrict__ W,
                                                short* __restrict__ Wt) {
    __shared__ short L[64 * 72];
    const int tid = threadIdx.x;
    const int kt = blockIdx.x >> 3, nt = blockIdx.x & 7;   // 16 x 8 tiles of 64x64
    const int k0 = kt * 64, n0 = nt * 64;
    {
        int r = tid >> 2, c0 = (tid & 3) * 16;   // k-row r, 16 n per thread
        const float* g = W + (size_t)(k0 + r) * DOUT + n0 + c0;
        float4 a0 = *reinterpret_cast<const float4*>(g);
        float4 a1 = *reinterpret_cast<const float4*>(g + 4);
        float4 a2 = *reinterpret_cast<const float4*>(g + 8);
        float4 a3 = *reinterpret_cast<const float4*>(g + 12);
        s8v p0, p1;
        p0[0]=f2bf(a0.x); p0[1]=f2bf(a0.y); p0[2]=f2bf(a0.z); p0[3]=f2bf(a0.w);
        p0[4]=f2bf(a1.x); p0[5]=f2bf(a1.y); p0[6]=f2bf(a1.z); p0[7]=f2bf(a1.w);
        p1[0]=f2bf(a2.x); p1[1]=f2bf(a2.y); p1[2]=f2bf(a2.z); p1[3]=f2bf(a2.w);
        p1[4]=f2bf(a3.x); p1[5]=f2bf(a3.y); p1[6]=f2bf(a3.z); p1[7]=f2bf(a3.w);
        *reinterpret_cast<s8v*>(&L[r * 72 + c0]) = p0;
        *reinterpret_cast<s8v*>(&L[r * 72 + c0 + 8]) = p1;
    }
    __syncthreads();
    {
        int n = tid >> 2, kc = (tid & 3) * 16;   // n-row, 16 k per thread
        s8v y0, y1;
#pragma unroll
        for (int j = 0; j < 8; ++j) y0[j] = L[(kc + j) * 72 + n];
#pragma unroll
        for (int j = 0; j < 8; ++j) y1[j] = L[(kc + 8 + j) * 72 + n];
        short* o = Wt + (size_t)(n0 + n) * KIN + k0 + kc;
        *reinterpret_cast<s8v*>(o) = y0;
        *reinterpret_cast<s8v*>(o + 8) = y1;
    }
}

// ---------------- prep: ccp = cc @ Wc + bc (fp32 + bf16), coalesced ----------------
__global__ __launch_bounds__(256) void k_prep_c(
    const float* __restrict__ cc, const float* __restrict__ Wc,
    const float* __restrict__ bc, float* __restrict__ ccp_f,
    short* __restrict__ ccp_bf) {
    __shared__ float ccs[512];
    const int tid = threadIdx.x, c = blockIdx.x;
    ccs[tid] = cc[c * DOUT + tid];
    ccs[tid + 256] = cc[c * DOUT + tid + 256];
    __syncthreads();
    float a0 = bc[tid], a1 = bc[tid + 256];
    for (int k = 0; k < DOUT; ++k) {
        float s = ccs[k];
        a0 += s * Wc[(size_t)k * DOUT + tid];
        a1 += s * Wc[(size_t)k * DOUT + tid + 256];
    }
    ccp_f[c * DOUT + tid] = a0;
    ccp_f[c * DOUT + tid + 256] = a1;
    ccp_bf[c * DOUT + tid] = f2bf(a0);
    ccp_bf[c * DOUT + tid + 256] = f2bf(a1);
}

// ---------------- GEMM1: proj & projT = A(fp32) @ W + b ----------------
// Double-buffered single-barrier pipeline: next-tile A regs + B global_load_lds
// issued BEFORE current-tile ds_read+MFMA; one __syncthreads per iter drains them.
// projT written via LDS bounce (128B-contiguous runs).
__global__ __launch_bounds__(256, 2) void k_gemm1(
    const float* __restrict__ A, const short* __restrict__ Wt,
    const float* __restrict__ bias, short* __restrict__ proj,
    short* __restrict__ projT) {
    __shared__ short smem[2 * 64 * 40 + 2 * 512 * 32];   // 75776 B
    short (*As)[64 * 40] = reinterpret_cast<short(*)[64 * 40]>(smem);
    short (*Bs)[512 * 32] = reinterpret_cast<short(*)[512 * 32]>(smem + 2 * 64 * 40);
    const int tid = threadIdx.x, lane = tid & 63, wv = tid >> 6;
    const int quad = lane >> 4, l15 = lane & 15;
    const int m0 = blockIdx.x * 64;

    f32x4 acc[4][8];
#pragma unroll
    for (int i = 0; i < 4; ++i)
#pragma unroll
        for (int j = 0; j < 8; ++j) acc[i][j] = (f32x4){0.f, 0.f, 0.f, 0.f};

    const int ar = tid >> 2;            // 0..63 A row
    const int ac2 = (tid & 3) * 8;      // 8-float group
    const float* Ag = A + (size_t)(m0 + ar) * KIN + ac2;

    // prologue: stage tile 0
    {
#pragma unroll
        for (int i = 0; i < 8; ++i) {   // B: 512x32 bf16 = 2048 chunks of 16B
            int c = i * 256 + tid;
            int n = c >> 2, kc = c & 3;
            load_lds16(Wt + (size_t)n * KIN + kc * 8,
                       &Bs[0][(i * 256 + wv * 64) * 8]);
        }
        float4 a0 = *reinterpret_cast<const float4*>(Ag);
        float4 a1 = *reinterpret_cast<const float4*>(Ag + 4);
        s8v p;
        p[0]=f2bf(a0.x); p[1]=f2bf(a0.y); p[2]=f2bf(a0.z); p[3]=f2bf(a0.w);
        p[4]=f2bf(a1.x); p[5]=f2bf(a1.y); p[6]=f2bf(a1.z); p[7]=f2bf(a1.w);
        *reinterpret_cast<s8v*>(&As[0][ar * 40 + ac2]) = p;
    }
    __syncthreads();

    int cur = 0;
    for (int it = 0; it < KIN / 32; ++it) {
        const bool pf = (it + 1 < KIN / 32);
        float4 a0, a1;
        if (pf) {
            const int k1 = (it + 1) * 32;
            a0 = *reinterpret_cast<const float4*>(Ag + k1);
            a1 = *reinterpret_cast<const float4*>(Ag + k1 + 4);
#pragma unroll
            for (int i = 0; i < 8; ++i) {
                int c = i * 256 + tid;
                int n = c >> 2, kc = c & 3;
                load_lds16(Wt + (size_t)n * KIN + k1 + kc * 8,
                           &Bs[cur ^ 1][(i * 256 + wv * 64) * 8]);
            }
        }
        bf16x8 af[4], bfr[8];
#pragma unroll
        for (int mi = 0; mi < 4; ++mi)
            af[mi] = *reinterpret_cast<const bf16x8*>(&As[cur][(mi * 16 + l15) * 40 + quad * 8]);
#pragma unroll
        for (int ni = 0; ni < 8; ++ni)
            bfr[ni] = *reinterpret_cast<const bf16x8*>(&Bs[cur][(wv * 128 + ni * 16 + l15) * 32 + quad * 8]);
#pragma unroll
        for (int mi = 0; mi < 4; ++mi)
#pragma unroll
            for (int ni = 0; ni < 8; ++ni)
                acc[mi][ni] = __builtin_amdgcn_mfma_f32_16x16x32_bf16(af[mi], bfr[ni], acc[mi][ni], 0, 0, 0);
        if (pf) {
            s8v p;
            p[0]=f2bf(a0.x); p[1]=f2bf(a0.y); p[2]=f2bf(a0.z); p[3]=f2bf(a0.w);
            p[4]=f2bf(a1.x); p[5]=f2bf(a1.y); p[6]=f2bf(a1.z); p[7]=f2bf(a1.w);
            *reinterpret_cast<s8v*>(&As[cur ^ 1][ar * 40 + ac2]) = p;
        }
        __syncthreads();
        cur ^= 1;
    }

    // epilogue: +bias; proj direct (32B segments); projT via LDS bounce.
    short* T = smem;   // [512][72] = 36864 shorts <= 37888 available
#pragma unroll
    for (int ni = 0; ni < 8; ++ni) {
        int col = wv * 128 + ni * 16 + l15;
        float bv = bias[col];
#pragma unroll
        for (int mi = 0; mi < 4; ++mi) {
            int ml = mi * 16 + quad * 4;
            s4v t;
#pragma unroll
            for (int r = 0; r < 4; ++r) {
                short v = f2bf(acc[mi][ni][r] + bv);
                t[r] = v;
                proj[(size_t)(m0 + ml + r) * DOUT + col] = v;
            }
            *reinterpret_cast<s4v*>(&T[col * 72 + ml]) = t;
        }
    }
    __syncthreads();
#pragma unroll
    for (int p = 0; p < 16; ++p) {
        int col = p * 32 + (tid >> 3);
        int ch = (tid & 7) * 8;
        s8v v = *reinterpret_cast<const s8v*>(&T[col * 72 + ch]);
        *reinterpret_cast<s8v*>(projT + (size_t)col * (Bn * Nn) + m0 + ch) = v;
    }
}

// ---------------- sims[b][c][n] = ccp . proj  (K=512) ----------------
// dbuf single-barrier pipeline. A tile 64x32 = exactly 256 chunks (1/thread).
__global__ __launch_bounds__(256) void k_sims(
    const short* __restrict__ ccp_bf, const short* __restrict__ proj,
    float* __restrict__ sims) {
    __shared__ short As[2][64 * 32];
    __shared__ short Bs[2][128 * 32];
    const int tid = threadIdx.x, lane = tid & 63, wv = tid >> 6;
    const int quad = lane >> 4, l15 = lane & 15;
    const int b = blockIdx.x >> 6, nt = blockIdx.x & 63;
    const int n0 = nt * 128;
    const int wm = wv & 1, wn = wv >> 1;

    f32x4 acc[2][4];
#pragma unroll
    for (int i = 0; i < 2; ++i)
#pragma unroll
        for (int j = 0; j < 4; ++j) acc[i][j] = (f32x4){0.f, 0.f, 0.f, 0.f};

    auto stage = [&](int buf, int k0) {
        {   // A: 64x32 = 256 chunks, one per thread
            int r = tid >> 2, kc = tid & 3;
            load_lds16(ccp_bf + (size_t)r * DOUT + k0 + kc * 8,
                       &As[buf][(wv * 64) * 8]);
        }
#pragma unroll
        for (int i = 0; i < 2; ++i) {   // B: 128x32 = 512 chunks
            int c = i * 256 + tid;
            int r = c >> 2, kc = c & 3;
            load_lds16(proj + (size_t)(b * Nn + n0 + r) * DOUT + k0 + kc * 8,
                       &Bs[buf][(i * 256 + wv * 64) * 8]);
        }
    };

    stage(0, 0);
    __syncthreads();
    int cur = 0;
    for (int it = 0; it < DOUT / 32; ++it) {
        if (it + 1 < DOUT / 32) stage(cur ^ 1, (it + 1) * 32);
        bf16x8 af[2], bfr[4];
#pragma unroll
        for (int mi = 0; mi < 2; ++mi)
            af[mi] = *reinterpret_cast<const bf16x8*>(&As[cur][(wm * 32 + mi * 16 + l15) * 32 + quad * 8]);
#pragma unroll
        for (int ni = 0; ni < 4; ++ni)
            bfr[ni] = *reinterpret_cast<const bf16x8*>(&Bs[cur][(wn * 64 + ni * 16 + l15) * 32 + quad * 8]);
#pragma unroll
        for (int mi = 0; mi < 2; ++mi)
#pragma unroll
            for (int ni = 0; ni < 4; ++ni)
                acc[mi][ni] = __builtin_amdgcn_mfma_f32_16x16x32_bf16(af[mi], bfr[ni], acc[mi][ni], 0, 0, 0);
        __syncthreads();
        cur ^= 1;
    }
#pragma unroll
    for (int mi = 0; mi < 2; ++mi)
#pragma unroll
        for (int ni = 0; ni < 4; ++ni)
#pragma unroll
            for (int r = 0; r < 4; ++r) {
                int c = wm * 32 + mi * 16 + quad * 4 + r;
                int n = n0 + wn * 64 + ni * 16 + l15;
                sims[((size_t)b * NC + c) * Nn + n] = acc[mi][ni][r];
            }
}

// ---------------- softmax over n (in-place on d_out) + bf16 copy ----------------
__global__ __launch_bounds__(256) void k_softmax(
    float* __restrict__ aw, const unsigned char* __restrict__ mask,
    short* __restrict__ aw_bf) {
    __shared__ float red[8];
    const int tid = threadIdx.x, lane = tid & 63, wv = tid >> 6;
    const int b = blockIdx.x >> 6, c = blockIdx.x & 63;
    float* p = aw + ((size_t)b * NC + c) * Nn;
    short* q = aw_bf + ((size_t)b * NC + c) * Nn;
    const unsigned char* mp = mask + b * Nn;

    float v[32];
    float mx = -INFINITY;
#pragma unroll
    for (int i = 0; i < 32; ++i) {
        int idx = tid + i * 256;
        float x = p[idx];
        if (mp[idx]) x = -INFINITY;
        v[i] = x;
        mx = fmaxf(mx, x);
    }
    for (int off = 32; off; off >>= 1) mx = fmaxf(mx, __shfl_xor(mx, off));
    if (lane == 0) red[wv] = mx;
    __syncthreads();
    mx = fmaxf(fmaxf(red[0], red[1]), fmaxf(red[2], red[3]));
    __syncthreads();

    float s = 0.f;
#pragma unroll
    for (int i = 0; i < 32; ++i) {
        v[i] = expf(v[i] - mx);
        s += v[i];
    }
    for (int off = 32; off; off >>= 1) s += __shfl_xor(s, off);
    if (lane == 0) red[wv] = s;
    __syncthreads();
    s = red[0] + red[1] + red[2] + red[3];
    float inv = 1.f / s;
#pragma unroll
    for (int i = 0; i < 32; ++i) {
        int idx = tid + i * 256;
        float w = v[i] * inv;
        p[idx] = w;
        q[idx] = f2bf(w);
    }
}

// ---------------- aggregation: partial[b][ks][c][d], split-K=8 ----------------
// dbuf single-barrier pipeline. A tile 64x32 = exactly 256 chunks (1/thread).
__global__ __launch_bounds__(256) void k_agg(
    const short* __restrict__ aw_bf, const short* __restrict__ projT,
    float* __restrict__ partial) {
    __shared__ short As[2][64 * 32];
    __shared__ short Bs[2][128 * 32];
    const int tid = threadIdx.x, lane = tid & 63, wv = tid >> 6;
    const int quad = lane >> 4, l15 = lane & 15;
    const int b = blockIdx.x >> 5, dt = (blockIdx.x >> 3) & 3, ksp = blockIdx.x & 7;
    const int d0 = dt * 128;
    const int wm = wv & 1, wn = wv >> 1;

    f32x4 acc[2][4];
#pragma unroll
    for (int i = 0; i < 2; ++i)
#pragma unroll
        for (int j = 0; j < 4; ++j) acc[i][j] = (f32x4){0.f, 0.f, 0.f, 0.f};

    auto stage = [&](int buf, int nb) {
        {   // A: 64c x 32n = 256 chunks, one per thread
            int r = tid >> 2, kc = tid & 3;
            load_lds16(aw_bf + ((size_t)b * NC + r) * Nn + nb + kc * 8,
                       &As[buf][(wv * 64) * 8]);
        }
#pragma unroll
        for (int i = 0; i < 2; ++i) {   // B: 128d x 32n = 512 chunks
            int c = i * 256 + tid;
            int r = c >> 2, kc = c & 3;
            load_lds16(projT + (size_t)(d0 + r) * (Bn * Nn) + b * Nn + nb + kc * 8,
                       &Bs[buf][(i * 256 + wv * 64) * 8]);
        }
    };

    stage(0, ksp * 1024);
    __syncthreads();
    int cur = 0;
    for (int it = 0; it < 32; ++it) {
        if (it + 1 < 32) stage(cur ^ 1, ksp * 1024 + (it + 1) * 32);
        bf16x8 af[2], bfr[4];
#pragma unroll
        for (int mi = 0; mi < 2; ++mi)
            af[mi] = *reinterpret_cast<const bf16x8*>(&As[cur][(wm * 32 + mi * 16 + l15) * 32 + quad * 8]);
#pragma unroll
        for (int ni = 0; ni < 4; ++ni)
            bfr[ni] = *reinterpret_cast<const bf16x8*>(&Bs[cur][(wn * 64 + ni * 16 + l15) * 32 + quad * 8]);
#pragma unroll
        for (int mi = 0; mi < 2; ++mi)
#pragma unroll
            for (int ni = 0; ni < 4; ++ni)
                acc[mi][ni] = __builtin_amdgcn_mfma_f32_16x16x32_bf16(af[mi], bfr[ni], acc[mi][ni], 0, 0, 0);
        __syncthreads();
        cur ^= 1;
    }
#pragma unroll
    for (int mi = 0; mi < 2; ++mi)
#pragma unroll
        for (int ni = 0; ni < 4; ++ni)
#pragma unroll
            for (int r = 0; r < 4; ++r) {
                int c = wm * 32 + mi * 16 + quad * 4 + r;
                int d = d0 + wn * 64 + ni * 16 + l15;
                partial[(((size_t)b * 8 + ksp) * NC + c) * DOUT + d] = acc[mi][ni][r];
            }
}

// ---------------- LN: sum partials + ccp residual, normalize, store ----------------
__global__ __launch_bounds__(256) void k_ln(
    const float* __restrict__ partial, const float* __restrict__ ccp,
    const float* __restrict__ gamma, const float* __restrict__ beta,
    float* __restrict__ out) {
    __shared__ float red[16];
    const int tid = threadIdx.x, lane = tid & 63, wv = tid >> 6;
    const int b = blockIdx.x >> 6, c = blockIdx.x & 63;
    float v0 = ccp[c * DOUT + tid], v1 = ccp[c * DOUT + tid + 256];
#pragma unroll
    for (int ks = 0; ks < 8; ++ks) {
        const float* pp = partial + (((size_t)b * 8 + ks) * NC + c) * DOUT;
        v0 += pp[tid];
        v1 += pp[tid + 256];
    }
    float s = v0 + v1, sq = v0 * v0 + v1 * v1;
    for (int off = 32; off; off >>= 1) {
        s += __shfl_xor(s, off);
        sq += __shfl_xor(sq, off);
    }
    if (lane == 0) { red[wv] = s; red[8 + wv] = sq; }
    __syncthreads();
    s = red[0] + red[1] + red[2] + red[3];
    sq = red[8] + red[9] + red[10] + red[11];
    float mu = s * (1.f / 512.f);
    float var = sq * (1.f / 512.f) - mu * mu;
    float rs = rsqrtf(var + LN_EPS);
    size_t base = ((size_t)b * NC + c) * DOUT;
    out[base + tid] = (v0 - mu) * rs * gamma[tid] + beta[tid];
    out[base + tid + 256] = (v1 - mu) * rs * gamma[tid + 256] + beta[tid + 256];
}

extern "C" void kernel_launch(void* const* d_in, const int* in_sizes, int n_in,
                              void* d_out, int out_size, void* d_ws, size_t ws_size,
                              hipStream_t stream) {
    const float* node_emb = (const float*)d_in[0];
    const unsigned char* mask = (const unsigned char*)d_in[1];
    const float* cc = (const float*)d_in[2];
    const float* Wn = (const float*)d_in[3];
    const float* bn = (const float*)d_in[4];
    const float* Wc = (const float*)d_in[5];
    const float* bc = (const float*)d_in[6];
    const float* gamma = (const float*)d_in[7];
    const float* beta = (const float*)d_in[8];
    float* out = (float*)d_out;

    char* ws = (char*)d_ws;
    short* proj   = (short*)(ws);                   //  67,108,864 B  [65536][512] bf16
    short* projT  = (short*)(ws + 67108864);        //  67,108,864 B  [512][65536] bf16
    short* aw_bf  = (short*)(ws + 134217728);       //   8,388,608 B  [8][64][8192] bf16
    float* ccp_f  = (float*)(ws + 142606336);       //     131,072 B
    short* ccp_bf = (short*)(ws + 142737408);       //      65,536 B
    short* Wt     = (short*)(ws + 142802944);       //   1,048,576 B  [512][1024] bf16
    float* partial= (float*)(ws + 143851520);       //   8,388,608 B  [8][8][64][512] f32

    float* sims = out + (size_t)Bn * NC * DOUT;     // aw region of d_out, scratch

    k_prep_w<<<128, 256, 0, stream>>>(Wn, Wt);
    k_prep_c<<<64, 256, 0, stream>>>(cc, Wc, bc, ccp_f, ccp_bf);
    k_gemm1<<<1024, 256, 0, stream>>>(node_emb, Wt, bn, proj, projT);
    k_sims<<<512, 256, 0, stream>>>(ccp_bf, proj, sims);
    k_softmax<<<512, 256, 0, stream>>>(sims, mask, aw_bf);
    k_agg<<<256, 256, 0, stream>>>(aw_bf, projT, partial);
    k_ln<<<512, 256, 0, stream>>>(partial, ccp_f, gamma, beta, out);
}

// Round 4
// 530.753 us; speedup vs baseline: 1.0694x; 1.0397x over previous
//
#include <hip/hip_runtime.h>
#include <hip/hip_bf16.h>
#include <math.h>

#define Bn 8
#define Nn 8192
#define KIN 1024
#define DOUT 512
#define NC 64
#define LN_EPS 1e-5f

typedef short bf16x8 __attribute__((ext_vector_type(8)));
typedef short s8v __attribute__((ext_vector_type(8)));
typedef short s4v __attribute__((ext_vector_type(4)));
typedef float f32x4 __attribute__((ext_vector_type(4)));

__device__ __forceinline__ short f2bf(float f) {
    __hip_bfloat16 h = __float2bfloat16(f);
    return __builtin_bit_cast(short, h);
}

__device__ __forceinline__ void load_lds16(const void* g, void* l) {
    __builtin_amdgcn_global_load_lds(
        (const __attribute__((address_space(1))) unsigned int*)g,
        (__attribute__((address_space(3))) unsigned int*)l, 16, 0, 0);
}

// ---------------- prep: W_node^T -> bf16 [512][1024], LDS transpose ----------------
__global__ __launch_bounds__(256) void k_prep_w(const float* __restrict__ W,
                                                short* __restrict__ Wt) {
    __shared__ short L[64 * 72];
    const int tid = threadIdx.x;
    const int kt = blockIdx.x >> 3, nt = blockIdx.x & 7;   // 16 x 8 tiles of 64x64
    const int k0 = kt * 64, n0 = nt * 64;
    {
        int r = tid >> 2, c0 = (tid & 3) * 16;   // k-row r, 16 n per thread
        const float* g = W + (size_t)(k0 + r) * DOUT + n0 + c0;
        float4 a0 = *reinterpret_cast<const float4*>(g);
        float4 a1 = *reinterpret_cast<const float4*>(g + 4);
        float4 a2 = *reinterpret_cast<const float4*>(g + 8);
        float4 a3 = *reinterpret_cast<const float4*>(g + 12);
        s8v p0, p1;
        p0[0]=f2bf(a0.x); p0[1]=f2bf(a0.y); p0[2]=f2bf(a0.z); p0[3]=f2bf(a0.w);
        p0[4]=f2bf(a1.x); p0[5]=f2bf(a1.y); p0[6]=f2bf(a1.z); p0[7]=f2bf(a1.w);
        p1[0]=f2bf(a2.x); p1[1]=f2bf(a2.y); p1[2]=f2bf(a2.z); p1[3]=f2bf(a2.w);
        p1[4]=f2bf(a3.x); p1[5]=f2bf(a3.y); p1[6]=f2bf(a3.z); p1[7]=f2bf(a3.w);
        *reinterpret_cast<s8v*>(&L[r * 72 + c0]) = p0;
        *reinterpret_cast<s8v*>(&L[r * 72 + c0 + 8]) = p1;
    }
    __syncthreads();
    {
        int n = tid >> 2, kc = (tid & 3) * 16;   // n-row, 16 k per thread
        s8v y0, y1;
#pragma unroll
        for (int j = 0; j < 8; ++j) y0[j] = L[(kc + j) * 72 + n];
#pragma unroll
        for (int j = 0; j < 8; ++j) y1[j] = L[(kc + 8 + j) * 72 + n];
        short* o = Wt + (size_t)(n0 + n) * KIN + k0 + kc;
        *reinterpret_cast<s8v*>(o) = y0;
        *reinterpret_cast<s8v*>(o + 8) = y1;
    }
}

// ---------------- prep: ccp = cc @ Wc + bc (fp32 + bf16), coalesced ----------------
__global__ __launch_bounds__(256) void k_prep_c(
    const float* __restrict__ cc, const float* __restrict__ Wc,
    const float* __restrict__ bc, float* __restrict__ ccp_f,
    short* __restrict__ ccp_bf) {
    __shared__ float ccs[512];
    const int tid = threadIdx.x, c = blockIdx.x;
    ccs[tid] = cc[c * DOUT + tid];
    ccs[tid + 256] = cc[c * DOUT + tid + 256];
    __syncthreads();
    float a0 = bc[tid], a1 = bc[tid + 256];
    for (int k = 0; k < DOUT; ++k) {
        float s = ccs[k];
        a0 += s * Wc[(size_t)k * DOUT + tid];
        a1 += s * Wc[(size_t)k * DOUT + tid + 256];
    }
    ccp_f[c * DOUT + tid] = a0;
    ccp_f[c * DOUT + tid + 256] = a1;
    ccp_bf[c * DOUT + tid] = f2bf(a0);
    ccp_bf[c * DOUT + tid + 256] = f2bf(a1);
}

// ---------------- GEMM1: proj & projT = A(fp32) @ W + b ----------------
// BM=128 x BN=512(full) x BK=32, 512 thr / 8 waves, wave tile 64x128.
// dbuf single-barrier pipeline. B-tile chunk-swizzled both-sides:
// LDS pos (n, kc^((n>>1)&3)) <- pre-swizzled global source; read quad^((l15>>1)&3).
// 8-way -> 2-way bank conflict on ds_read_b128 fragments.
// projT written via LDS bounce in two wm-half passes.
__global__ __launch_bounds__(512, 2) void k_gemm1(
    const float* __restrict__ A, const short* __restrict__ Wt,
    const float* __restrict__ bias, short* __restrict__ proj,
    short* __restrict__ projT) {
    __shared__ short smem[2 * 128 * 40 + 2 * 512 * 32];   // 86016 B
    short (*As)[128 * 40] = reinterpret_cast<short(*)[128 * 40]>(smem);
    short (*Bs)[512 * 32] = reinterpret_cast<short(*)[512 * 32]>(smem + 2 * 128 * 40);
    const int tid = threadIdx.x, lane = tid & 63, wv = tid >> 6;
    const int quad = lane >> 4, l15 = lane & 15;
    const int wm = wv & 1, wn = wv >> 1;       // 2M x 4N wave grid
    const int m0 = blockIdx.x * 128;
    const int qs = quad ^ ((l15 >> 1) & 3);    // swizzled read chunk

    f32x4 acc[4][8];
#pragma unroll
    for (int i = 0; i < 4; ++i)
#pragma unroll
        for (int j = 0; j < 8; ++j) acc[i][j] = (f32x4){0.f, 0.f, 0.f, 0.f};

    const int ar = tid >> 2;            // 0..127 A row
    const int ac2 = (tid & 3) * 8;      // 8-float group
    const float* Ag = A + (size_t)(m0 + ar) * KIN + ac2;

    // prologue: stage tile 0
    {
#pragma unroll
        for (int i = 0; i < 4; ++i) {   // B: 512x32 bf16 = 2048 chunks of 16B
            int c = i * 512 + tid;
            int n = c >> 2, kc = c & 3;
            int kq = kc ^ ((n >> 1) & 3);
            load_lds16(Wt + (size_t)n * KIN + kq * 8,
                       &Bs[0][(i * 512 + wv * 64) * 8]);
        }
        float4 a0 = *reinterpret_cast<const float4*>(Ag);
        float4 a1 = *reinterpret_cast<const float4*>(Ag + 4);
        s8v p;
        p[0]=f2bf(a0.x); p[1]=f2bf(a0.y); p[2]=f2bf(a0.z); p[3]=f2bf(a0.w);
        p[4]=f2bf(a1.x); p[5]=f2bf(a1.y); p[6]=f2bf(a1.z); p[7]=f2bf(a1.w);
        *reinterpret_cast<s8v*>(&As[0][ar * 40 + ac2]) = p;
    }
    __syncthreads();

    int cur = 0;
    for (int it = 0; it < KIN / 32; ++it) {
        const bool pf = (it + 1 < KIN / 32);
        float4 a0, a1;
        if (pf) {
            const int k1 = (it + 1) * 32;
            a0 = *reinterpret_cast<const float4*>(Ag + k1);
            a1 = *reinterpret_cast<const float4*>(Ag + k1 + 4);
#pragma unroll
            for (int i = 0; i < 4; ++i) {
                int c = i * 512 + tid;
                int n = c >> 2, kc = c & 3;
                int kq = kc ^ ((n >> 1) & 3);
                load_lds16(Wt + (size_t)n * KIN + k1 + kq * 8,
                           &Bs[cur ^ 1][(i * 512 + wv * 64) * 8]);
            }
        }
        bf16x8 af[4], bfr[8];
#pragma unroll
        for (int mi = 0; mi < 4; ++mi)
            af[mi] = *reinterpret_cast<const bf16x8*>(&As[cur][(wm * 64 + mi * 16 + l15) * 40 + quad * 8]);
#pragma unroll
        for (int ni = 0; ni < 8; ++ni)
            bfr[ni] = *reinterpret_cast<const bf16x8*>(&Bs[cur][(wn * 128 + ni * 16 + l15) * 32 + qs * 8]);
#pragma unroll
        for (int mi = 0; mi < 4; ++mi)
#pragma unroll
            for (int ni = 0; ni < 8; ++ni)
                acc[mi][ni] = __builtin_amdgcn_mfma_f32_16x16x32_bf16(af[mi], bfr[ni], acc[mi][ni], 0, 0, 0);
        if (pf) {
            s8v p;
            p[0]=f2bf(a0.x); p[1]=f2bf(a0.y); p[2]=f2bf(a0.z); p[3]=f2bf(a0.w);
            p[4]=f2bf(a1.x); p[5]=f2bf(a1.y); p[6]=f2bf(a1.z); p[7]=f2bf(a1.w);
            *reinterpret_cast<s8v*>(&As[cur ^ 1][ar * 40 + ac2]) = p;
        }
        __syncthreads();
        cur ^= 1;
    }

    // epilogue: +bias; proj direct; projT via LDS bounce in two wm-half passes.
    short* T = smem;   // [512][72] = 36864 shorts <= 43008 available
    float bv[8];
#pragma unroll
    for (int ni = 0; ni < 8; ++ni) bv[ni] = bias[wn * 128 + ni * 16 + l15];

#pragma unroll
    for (int h = 0; h < 2; ++h) {
        if (wm == h) {
#pragma unroll
            for (int ni = 0; ni < 8; ++ni) {
                int col = wn * 128 + ni * 16 + l15;
#pragma unroll
                for (int mi = 0; mi < 4; ++mi) {
                    int ml = mi * 16 + quad * 4;   // local row within half
                    s4v t;
#pragma unroll
                    for (int r = 0; r < 4; ++r) {
                        short v = f2bf(acc[mi][ni][r] + bv[ni]);
                        t[r] = v;
                        proj[(size_t)(m0 + h * 64 + ml + r) * DOUT + col] = v;
                    }
                    *reinterpret_cast<s4v*>(&T[col * 72 + ml]) = t;
                }
            }
        }
        __syncthreads();
#pragma unroll
        for (int p = 0; p < 8; ++p) {
            int col = p * 64 + (tid >> 3);
            int ch = (tid & 7) * 8;
            s8v v = *reinterpret_cast<const s8v*>(&T[col * 72 + ch]);
            *reinterpret_cast<s8v*>(projT + (size_t)col * (Bn * Nn) + m0 + h * 64 + ch) = v;
        }
        __syncthreads();
    }
}

// ---------------- sims[b][c][n] = ccp . proj  (K=512) ----------------
// dbuf single-barrier pipeline + both-sides chunk swizzle on A and B tiles.
__global__ __launch_bounds__(256) void k_sims(
    const short* __restrict__ ccp_bf, const short* __restrict__ proj,
    float* __restrict__ sims) {
    __shared__ short As[2][64 * 32];
    __shared__ short Bs[2][128 * 32];
    const int tid = threadIdx.x, lane = tid & 63, wv = tid >> 6;
    const int quad = lane >> 4, l15 = lane & 15;
    const int b = blockIdx.x >> 6, nt = blockIdx.x & 63;
    const int n0 = nt * 128;
    const int wm = wv & 1, wn = wv >> 1;
    const int qs = quad ^ ((l15 >> 1) & 3);

    f32x4 acc[2][4];
#pragma unroll
    for (int i = 0; i < 2; ++i)
#pragma unroll
        for (int j = 0; j < 4; ++j) acc[i][j] = (f32x4){0.f, 0.f, 0.f, 0.f};

    auto stage = [&](int buf, int k0) {
        {   // A: 64x32 = 256 chunks, one per thread
            int r = tid >> 2, kc = tid & 3;
            int kq = kc ^ ((r >> 1) & 3);
            load_lds16(ccp_bf + (size_t)r * DOUT + k0 + kq * 8,
                       &As[buf][(wv * 64) * 8]);
        }
#pragma unroll
        for (int i = 0; i < 2; ++i) {   // B: 128x32 = 512 chunks
            int c = i * 256 + tid;
            int r = c >> 2, kc = c & 3;
            int kq = kc ^ ((r >> 1) & 3);
            load_lds16(proj + (size_t)(b * Nn + n0 + r) * DOUT + k0 + kq * 8,
                       &Bs[buf][(i * 256 + wv * 64) * 8]);
        }
    };

    stage(0, 0);
    __syncthreads();
    int cur = 0;
    for (int it = 0; it < DOUT / 32; ++it) {
        if (it + 1 < DOUT / 32) stage(cur ^ 1, (it + 1) * 32);
        bf16x8 af[2], bfr[4];
#pragma unroll
        for (int mi = 0; mi < 2; ++mi)
            af[mi] = *reinterpret_cast<const bf16x8*>(&As[cur][(wm * 32 + mi * 16 + l15) * 32 + qs * 8]);
#pragma unroll
        for (int ni = 0; ni < 4; ++ni)
            bfr[ni] = *reinterpret_cast<const bf16x8*>(&Bs[cur][(wn * 64 + ni * 16 + l15) * 32 + qs * 8]);
#pragma unroll
        for (int mi = 0; mi < 2; ++mi)
#pragma unroll
            for (int ni = 0; ni < 4; ++ni)
                acc[mi][ni] = __builtin_amdgcn_mfma_f32_16x16x32_bf16(af[mi], bfr[ni], acc[mi][ni], 0, 0, 0);
        __syncthreads();
        cur ^= 1;
    }
#pragma unroll
    for (int mi = 0; mi < 2; ++mi)
#pragma unroll
        for (int ni = 0; ni < 4; ++ni)
#pragma unroll
            for (int r = 0; r < 4; ++r) {
                int c = wm * 32 + mi * 16 + quad * 4 + r;
                int n = n0 + wn * 64 + ni * 16 + l15;
                sims[((size_t)b * NC + c) * Nn + n] = acc[mi][ni][r];
            }
}

// ---------------- softmax over n (in-place on d_out) + bf16 copy ----------------
__global__ __launch_bounds__(256) void k_softmax(
    float* __restrict__ aw, const unsigned char* __restrict__ mask,
    short* __restrict__ aw_bf) {
    __shared__ float red[8];
    const int tid = threadIdx.x, lane = tid & 63, wv = tid >> 6;
    const int b = blockIdx.x >> 6, c = blockIdx.x & 63;
    float* p = aw + ((size_t)b * NC + c) * Nn;
    short* q = aw_bf + ((size_t)b * NC + c) * Nn;
    const unsigned char* mp = mask + b * Nn;

    float v[32];
    float mx = -INFINITY;
#pragma unroll
    for (int i = 0; i < 32; ++i) {
        int idx = tid + i * 256;
        float x = p[idx];
        if (mp[idx]) x = -INFINITY;
        v[i] = x;
        mx = fmaxf(mx, x);
    }
    for (int off = 32; off; off >>= 1) mx = fmaxf(mx, __shfl_xor(mx, off));
    if (lane == 0) red[wv] = mx;
    __syncthreads();
    mx = fmaxf(fmaxf(red[0], red[1]), fmaxf(red[2], red[3]));
    __syncthreads();

    float s = 0.f;
#pragma unroll
    for (int i = 0; i < 32; ++i) {
        v[i] = expf(v[i] - mx);
        s += v[i];
    }
    for (int off = 32; off; off >>= 1) s += __shfl_xor(s, off);
    if (lane == 0) red[wv] = s;
    __syncthreads();
    s = red[0] + red[1] + red[2] + red[3];
    float inv = 1.f / s;
#pragma unroll
    for (int i = 0; i < 32; ++i) {
        int idx = tid + i * 256;
        float w = v[i] * inv;
        p[idx] = w;
        q[idx] = f2bf(w);
    }
}

// ---------------- aggregation: partial[b][ks][c][d], split-K=8 ----------------
// dbuf single-barrier pipeline + both-sides chunk swizzle.
__global__ __launch_bounds__(256) void k_agg(
    const short* __restrict__ aw_bf, const short* __restrict__ projT,
    float* __restrict__ partial) {
    __shared__ short As[2][64 * 32];
    __shared__ short Bs[2][128 * 32];
    const int tid = threadIdx.x, lane = tid & 63, wv = tid >> 6;
    const int quad = lane >> 4, l15 = lane & 15;
    const int b = blockIdx.x >> 5, dt = (blockIdx.x >> 3) & 3, ksp = blockIdx.x & 7;
    const int d0 = dt * 128;
    const int wm = wv & 1, wn = wv >> 1;
    const int qs = quad ^ ((l15 >> 1) & 3);

    f32x4 acc[2][4];
#pragma unroll
    for (int i = 0; i < 2; ++i)
#pragma unroll
        for (int j = 0; j < 4; ++j) acc[i][j] = (f32x4){0.f, 0.f, 0.f, 0.f};

    auto stage = [&](int buf, int nb) {
        {   // A: 64c x 32n = 256 chunks, one per thread
            int r = tid >> 2, kc = tid & 3;
            int kq = kc ^ ((r >> 1) & 3);
            load_lds16(aw_bf + ((size_t)b * NC + r) * Nn + nb + kq * 8,
                       &As[buf][(wv * 64) * 8]);
        }
#pragma unroll
        for (int i = 0; i < 2; ++i) {   // B: 128d x 32n = 512 chunks
            int c = i * 256 + tid;
            int r = c >> 2, kc = c & 3;
            int kq = kc ^ ((r >> 1) & 3);
            load_lds16(projT + (size_t)(d0 + r) * (Bn * Nn) + b * Nn + nb + kq * 8,
                       &Bs[buf][(i * 256 + wv * 64) * 8]);
        }
    };

    stage(0, ksp * 1024);
    __syncthreads();
    int cur = 0;
    for (int it = 0; it < 32; ++it) {
        if (it + 1 < 32) stage(cur ^ 1, ksp * 1024 + (it + 1) * 32);
        bf16x8 af[2], bfr[4];
#pragma unroll
        for (int mi = 0; mi < 2; ++mi)
            af[mi] = *reinterpret_cast<const bf16x8*>(&As[cur][(wm * 32 + mi * 16 + l15) * 32 + qs * 8]);
#pragma unroll
        for (int ni = 0; ni < 4; ++ni)
            bfr[ni] = *reinterpret_cast<const bf16x8*>(&Bs[cur][(wn * 64 + ni * 16 + l15) * 32 + qs * 8]);
#pragma unroll
        for (int mi = 0; mi < 2; ++mi)
#pragma unroll
            for (int ni = 0; ni < 4; ++ni)
                acc[mi][ni] = __builtin_amdgcn_mfma_f32_16x16x32_bf16(af[mi], bfr[ni], acc[mi][ni], 0, 0, 0);
        __syncthreads();
        cur ^= 1;
    }
#pragma unroll
    for (int mi = 0; mi < 2; ++mi)
#pragma unroll
        for (int ni = 0; ni < 4; ++ni)
#pragma unroll
            for (int r = 0; r < 4; ++r) {
                int c = wm * 32 + mi * 16 + quad * 4 + r;
                int d = d0 + wn * 64 + ni * 16 + l15;
                partial[(((size_t)b * 8 + ksp) * NC + c) * DOUT + d] = acc[mi][ni][r];
            }
}

// ---------------- LN: sum partials + ccp residual, normalize, store ----------------
__global__ __launch_bounds__(256) void k_ln(
    const float* __restrict__ partial, const float* __restrict__ ccp,
    const float* __restrict__ gamma, const float* __restrict__ beta,
    float* __restrict__ out) {
    __shared__ float red[16];
    const int tid = threadIdx.x, lane = tid & 63, wv = tid >> 6;
    const int b = blockIdx.x >> 6, c = blockIdx.x & 63;
    float v0 = ccp[c * DOUT + tid], v1 = ccp[c * DOUT + tid + 256];
#pragma unroll
    for (int ks = 0; ks < 8; ++ks) {
        const float* pp = partial + (((size_t)b * 8 + ks) * NC + c) * DOUT;
        v0 += pp[tid];
        v1 += pp[tid + 256];
    }
    float s = v0 + v1, sq = v0 * v0 + v1 * v1;
    for (int off = 32; off; off >>= 1) {
        s += __shfl_xor(s, off);
        sq += __shfl_xor(sq, off);
    }
    if (lane == 0) { red[wv] = s; red[8 + wv] = sq; }
    __syncthreads();
    s = red[0] + red[1] + red[2] + red[3];
    sq = red[8] + red[9] + red[10] + red[11];
    float mu = s * (1.f / 512.f);
    float var = sq * (1.f / 512.f) - mu * mu;
    float rs = rsqrtf(var + LN_EPS);
    size_t base = ((size_t)b * NC + c) * DOUT;
    out[base + tid] = (v0 - mu) * rs * gamma[tid] + beta[tid];
    out[base + tid + 256] = (v1 - mu) * rs * gamma[tid + 256] + beta[tid + 256];
}

extern "C" void kernel_launch(void* const* d_in, const int* in_sizes, int n_in,
                              void* d_out, int out_size, void* d_ws, size_t ws_size,
                              hipStream_t stream) {
    const float* node_emb = (const float*)d_in[0];
    const unsigned char* mask = (const unsigned char*)d_in[1];
    const float* cc = (const float*)d_in[2];
    const float* Wn = (const float*)d_in[3];
    const float* bn = (const float*)d_in[4];
    const float* Wc = (const float*)d_in[5];
    const float* bc = (const float*)d_in[6];
    const float* gamma = (const float*)d_in[7];
    const float* beta = (const float*)d_in[8];
    float* out = (float*)d_out;

    char* ws = (char*)d_ws;
    short* proj   = (short*)(ws);                   //  67,108,864 B  [65536][512] bf16
    short* projT  = (short*)(ws + 67108864);        //  67,108,864 B  [512][65536] bf16
    short* aw_bf  = (short*)(ws + 134217728);       //   8,388,608 B  [8][64][8192] bf16
    float* ccp_f  = (float*)(ws + 142606336);       //     131,072 B
    short* ccp_bf = (short*)(ws + 142737408);       //      65,536 B
    short* Wt     = (short*)(ws + 142802944);       //   1,048,576 B  [512][1024] bf16
    float* partial= (float*)(ws + 143851520);       //   8,388,608 B  [8][8][64][512] f32

    float* sims = out + (size_t)Bn * NC * DOUT;     // aw region of d_out, scratch

    k_prep_w<<<128, 256, 0, stream>>>(Wn, Wt);
    k_prep_c<<<64, 256, 0, stream>>>(cc, Wc, bc, ccp_f, ccp_bf);
    k_gemm1<<<512, 512, 0, stream>>>(node_emb, Wt, bn, proj, projT);
    k_sims<<<512, 256, 0, stream>>>(ccp_bf, proj, sims);
    k_softmax<<<512, 256, 0, stream>>>(sims, mask, aw_bf);
    k_agg<<<256, 256, 0, stream>>>(aw_bf, projT, partial);
    k_ln<<<512, 256, 0, stream>>>(partial, ccp_f, gamma, beta, out);
}